// Round 1
// baseline (806.441 us; speedup 1.0000x reference)
//
#include <hip/hip_runtime.h>

#define S_LEN 2048
#define D_DIM 128
#define BM 128
#define BK 64
#define NIT (S_LEN / BK)
#define LQ 136   // Ks row stride (bf16 elems): 272 B = 17*16 -> 16B-aligned, 8-slot-balanced banks
#define LV 72    // Vt row stride (bf16 elems): 144 B = 9*16

typedef __attribute__((ext_vector_type(8))) short bf16x8;  // 8 bf16 (4 VGPRs)
typedef __attribute__((ext_vector_type(4))) float f32x4;   // MFMA accumulator
typedef __attribute__((ext_vector_type(4))) int i32x4;

// Single-instruction RNE pack of two f32 -> packed bf16x2 (no builtin on gfx950).
__device__ __forceinline__ unsigned cvtpk(float lo, float hi) {
    unsigned r;
    asm("v_cvt_pk_bf16_f32 %0, %1, %2" : "=v"(r) : "v"(lo), "v"(hi));
    return r;
}
__device__ __forceinline__ bf16x8 pack8(float4 a, float4 b) {
    union { unsigned u[4]; bf16x8 v; } r;
    r.u[0] = cvtpk(a.x, a.y);
    r.u[1] = cvtpk(a.z, a.w);
    r.u[2] = cvtpk(b.x, b.y);
    r.u[3] = cvtpk(b.z, b.w);
    return r.v;
}

// One block: 128 Q-rows of one (b,h); 32 iters over t-chunks of 64.
// Software-pipelined: K/V global loads for it+1 are issued right after the
// barrier of iter it and only waited at the pack+ds_write at the TOP of
// iter it+1 (rotated loop) -> HBM latency hides under S-gemm/P/O-gemm.
// Double-buffered Ks/Vt; ONE raw barrier per iter (lgkmcnt-only drain, so
// in-flight global loads survive the barrier). Q lives in registers.
// LDS = 71.7 KB -> 2 blocks/CU (8 waves/CU).
__global__ __launch_bounds__(256, 2)
void fused_qkmv(const float* __restrict__ q, const float* __restrict__ k,
                const float* __restrict__ v, const float* __restrict__ mask,
                float* __restrict__ out) {
    __shared__ __align__(16) unsigned short Ks[2][BK * LQ];     // K[t][d] bf16, x2
    __shared__ __align__(16) unsigned short Vt[2][D_DIM * LV];  // V^T[d][t] bf16, x2

    const int tid  = threadIdx.x;
    const int lane = tid & 63;
    const int w    = tid >> 6;   // wave 0..3: s-range 32w..32w+32
    const int l15  = lane & 15;
    const int qd   = lane >> 4;  // quad

    // XCD-chunked swizzle: 512 blocks / 8 XCDs = 64 contiguous logical wgs per
    // XCD -> all 16 q-tiles of a head share one XCD's L2 for K/V.
    const int bid = (int)blockIdx.x;
    const int wg  = (bid & 7) * 64 + (bid >> 3);
    const int bh  = wg >> 4;
    const int s0  = (wg & 15) * BM;

    const float* qp = q + (size_t)bh * S_LEN * D_DIM;
    const float* kp = k + (size_t)bh * S_LEN * D_DIM;
    const float* vp = v + (size_t)bh * S_LEN * D_DIM;
    const float* mp = mask + (size_t)bh * S_LEN * S_LEN;
    float*       op = out + (size_t)bh * S_LEN * D_DIM;

    // staging thread mapping
    const int tk = tid >> 2;         // K row (t): 0..63
    const int ck = (tid & 3) * 8;    // K col (d) base; chunks at +32*i (b128 writes)
    const int tg = (tid & 15) * 4;   // V t-base
    const int dg = (tid >> 4) * 8;   // V d-base

    // ---- issue K/V global loads for it=0 (waited at first pack) ----
    float4 kr[8], va[4], vbr[4];
#pragma unroll
    for (int i = 0; i < 4; ++i) {
        const float* kb = kp + (size_t)tk * D_DIM + ck + 32 * i;
        kr[2 * i]     = *(const float4*)kb;
        kr[2 * i + 1] = *(const float4*)(kb + 4);
    }
#pragma unroll
    for (int r = 0; r < 4; ++r) {
        const float* vb = vp + (size_t)(tg + r) * D_DIM + dg;
        va[r]  = *(const float4*)vb;
        vbr[r] = *(const float4*)(vb + 4);
    }

    // ---- mask loads for it=0 ----
    const float* mbase = mp + (size_t)(s0 + 32 * w + l15) * S_LEN + 4 * qd;
    float4 mreg[4][2];  // [ti][sj]
#pragma unroll
    for (int ti = 0; ti < 4; ++ti)
#pragma unroll
        for (int sj = 0; sj < 2; ++sj)
            mreg[ti][sj] = *(const float4*)(mbase + (size_t)sj * 16 * S_LEN + ti * 16);

    // ---- Q tile -> registers (S-gemm B-fragments), loaded once ----
    bf16x8 qreg[2][4];  // [sj][kc]
#pragma unroll
    for (int sj = 0; sj < 2; ++sj) {
        const float* qb = qp + (size_t)(s0 + 32 * w + 16 * sj + l15) * D_DIM + qd * 8;
#pragma unroll
        for (int kc = 0; kc < 4; ++kc) {
            float4 f0 = *(const float4*)(qb + kc * 32);
            float4 f1 = *(const float4*)(qb + kc * 32 + 4);
            qreg[sj][kc] = pack8(f0, f1);
        }
    }

    f32x4 acc_o[2][8];
#pragma unroll
    for (int i = 0; i < 2; ++i)
#pragma unroll
        for (int j = 0; j < 8; ++j) acc_o[i][j] = (f32x4){0.f, 0.f, 0.f, 0.f};

    // bpermute source-lane byte addresses (src quad = 2*(qd&1) [+1], same l15)
    const int a0 = ((2 * (qd & 1)) * 16 + l15) * 4;
    const int a1 = a0 + 64;
    const bool hi = (qd >= 2);

#pragma unroll 2
    for (int it = 0; it < NIT; ++it) {
        const int cur = it & 1;
        const int t0n = ((it + 1) & (NIT - 1)) * BK;  // wrapped: last-iter prefetch is harmless

        // ---- pack + write staged K/V for THIS iter (first wait on kr/va/vbr) ----
#pragma unroll
        for (int i = 0; i < 4; ++i)
            *(bf16x8*)&Ks[cur][tk * LQ + ck + 32 * i] = pack8(kr[2 * i], kr[2 * i + 1]);
#pragma unroll
        for (int i = 0; i < 4; ++i) {
            uint2 w0, w1;
            w0.x = cvtpk(((const float*)&va[0])[i], ((const float*)&va[1])[i]);
            w0.y = cvtpk(((const float*)&va[2])[i], ((const float*)&va[3])[i]);
            *(uint2*)&Vt[cur][(dg + i) * LV + tg] = w0;
            w1.x = cvtpk(((const float*)&vbr[0])[i], ((const float*)&vbr[1])[i]);
            w1.y = cvtpk(((const float*)&vbr[2])[i], ((const float*)&vbr[3])[i]);
            *(uint2*)&Vt[cur][(dg + 4 + i) * LV + tg] = w1;
        }

        // LDS-only drain + raw barrier: next-iter mask loads (and anything else
        // in the vmcnt queue) stay in flight across the barrier.
        asm volatile("s_waitcnt lgkmcnt(0)" ::: "memory");
        __builtin_amdgcn_s_barrier();

        // ---- issue K/V global loads for it+1 (consumed at next iter's top) ----
#pragma unroll
        for (int i = 0; i < 4; ++i) {
            const float* kb = kp + (size_t)(t0n + tk) * D_DIM + ck + 32 * i;
            kr[2 * i]     = *(const float4*)kb;
            kr[2 * i + 1] = *(const float4*)(kb + 4);
        }
#pragma unroll
        for (int r = 0; r < 4; ++r) {
            const float* vb = vp + (size_t)(t0n + tg + r) * D_DIM + dg;
            va[r]  = *(const float4*)vb;
            vbr[r] = *(const float4*)(vb + 4);
        }

        // ---- S^T = K·Q^T : A=K[t][d], B=Q^T; tiles ti(t) x sj(s) ----
        f32x4 acc_s[4][2];
#pragma unroll
        for (int i = 0; i < 4; ++i)
#pragma unroll
            for (int j = 0; j < 2; ++j) acc_s[i][j] = (f32x4){0.f, 0.f, 0.f, 0.f};
#pragma unroll
        for (int kc = 0; kc < 4; ++kc) {
            const int ko = kc * 32 + qd * 8;
            bf16x8 af[4];
#pragma unroll
            for (int ti = 0; ti < 4; ++ti)
                af[ti] = *(const bf16x8*)&Ks[cur][(16 * ti + l15) * LQ + ko];
#pragma unroll
            for (int ti = 0; ti < 4; ++ti)
#pragma unroll
                for (int sj = 0; sj < 2; ++sj)
                    acc_s[ti][sj] = __builtin_amdgcn_mfma_f32_16x16x32_bf16(
                        af[ti], qreg[sj][kc], acc_s[ti][sj], 0, 0, 0);
        }

        // ---- P = S^T ∘ mask -> packed bf16 ----
        int pu[4][2][2];
#pragma unroll
        for (int ti = 0; ti < 4; ++ti)
#pragma unroll
            for (int sj = 0; sj < 2; ++sj) {
                f32x4 sv = acc_s[ti][sj];
                float4 m = mreg[ti][sj];
                pu[ti][sj][0] = (int)cvtpk(sv[0] * m.x, sv[1] * m.y);
                pu[ti][sj][1] = (int)cvtpk(sv[2] * m.z, sv[3] * m.w);
            }

        // ---- issue mask loads for it+1 (regs just freed; consumed next iter) ----
#pragma unroll
        for (int ti = 0; ti < 4; ++ti)
#pragma unroll
            for (int sj = 0; sj < 2; ++sj)
                mreg[ti][sj] = *(const float4*)(mbase + t0n + (size_t)sj * 16 * S_LEN + ti * 16);

        // ---- quad-exchange to O-gemm A-layout + O += P·V ----
#pragma unroll
        for (int kc2 = 0; kc2 < 2; ++kc2) {
            bf16x8 ap[2];
#pragma unroll
            for (int sj = 0; sj < 2; ++sj) {
                const int tA = 2 * kc2, tB = 2 * kc2 + 1;
                int w0a = __builtin_amdgcn_ds_bpermute(a0, pu[tA][sj][0]);
                int w0b = __builtin_amdgcn_ds_bpermute(a0, pu[tB][sj][0]);
                int w1a = __builtin_amdgcn_ds_bpermute(a0, pu[tA][sj][1]);
                int w1b = __builtin_amdgcn_ds_bpermute(a0, pu[tB][sj][1]);
                int w2a = __builtin_amdgcn_ds_bpermute(a1, pu[tA][sj][0]);
                int w2b = __builtin_amdgcn_ds_bpermute(a1, pu[tB][sj][0]);
                int w3a = __builtin_amdgcn_ds_bpermute(a1, pu[tA][sj][1]);
                int w3b = __builtin_amdgcn_ds_bpermute(a1, pu[tB][sj][1]);
                union { i32x4 i; bf16x8 b; } u;
                u.i = (i32x4){hi ? w0b : w0a, hi ? w1b : w1a,
                              hi ? w2b : w2a, hi ? w3b : w3a};
                ap[sj] = u.b;
            }
            const int ko = kc2 * 32 + qd * 8;
#pragma unroll
            for (int dj = 0; dj < 8; ++dj) {
                bf16x8 bv = *(const bf16x8*)&Vt[cur][(16 * dj + l15) * LV + ko];
#pragma unroll
                for (int si = 0; si < 2; ++si)
                    acc_o[si][dj] = __builtin_amdgcn_mfma_f32_16x16x32_bf16(
                        ap[si], bv, acc_o[si][dj], 0, 0, 0);
            }
        }
    }

    // ---- epilogue: O[s][d], C-layout row=4qd+r, col=l15 ----
#pragma unroll
    for (int si = 0; si < 2; ++si)
#pragma unroll
        for (int dj = 0; dj < 8; ++dj) {
#pragma unroll
            for (int r = 0; r < 4; ++r) {
                const int srow = s0 + 32 * w + 16 * si + 4 * qd + r;
                op[(size_t)srow * D_DIM + 16 * dj + l15] = acc_o[si][dj][r];
            }
        }
}

extern "C" void kernel_launch(void* const* d_in, const int* in_sizes, int n_in,
                              void* d_out, int out_size, void* d_ws, size_t ws_size,
                              hipStream_t stream) {
    const float* q = (const float*)d_in[0];
    const float* k = (const float*)d_in[1];
    const float* v = (const float*)d_in[2];
    const float* m = (const float*)d_in[3];
    float* out = (float*)d_out;
    // 32 heads * 16 q-tiles = 512 blocks; 2 blocks/CU co-resident
    fused_qkmv<<<dim3(512), dim3(256), 0, stream>>>(q, k, v, m, out);
}